// Round 4
// baseline (806.222 us; speedup 1.0000x reference)
//
#include <hip/hip_runtime.h>
#include <hip/hip_bf16.h>

typedef __attribute__((ext_vector_type(8))) __bf16 bf16x8;
typedef __attribute__((ext_vector_type(4))) float f32x4;

#define TM 32          // rows per block
#define LDXM 40        // masked-x tile stride
#define LDH 136        // h tile stride
#define LDP 416        // params tile stride = 16 dims * 26
#define MIN_BIN 1e-4f
#define MIN_SLOPE 1e-4f

// load 8 contiguous fp32, round-to-nearest-even to bf16x8
__device__ inline bf16x8 cvt8(const float* __restrict__ p) {
    f32x4 a = *(const f32x4*)p;
    f32x4 b = *(const f32x4*)(p + 4);
    bf16x8 r;
    r[0] = (__bf16)a[0]; r[1] = (__bf16)a[1]; r[2] = (__bf16)a[2]; r[3] = (__bf16)a[3];
    r[4] = (__bf16)b[0]; r[5] = (__bf16)b[1]; r[6] = (__bf16)b[2]; r[7] = (__bf16)b[3];
    return r;
}

// ---- one dense layer: hout = relu(hin @ W^T + b), N=128, via MFMA 16x16x32 ----
// A-frag: lane reads hin[m0+(l&15)][kt*32 + (l>>4)*8 .. +8]  (bf16 LDS)
// B-frag: lane reads W[(n0+(l&15))*K + kt*32 + (l>>4)*8 .. +8]  (fp32 global -> cvt)
// C/D:    col = n0+(l&15), row = m0 + (l>>4)*4 + reg
template<int K, int LDIN>
__device__ inline void dense_layer(const float* __restrict__ Wg,
                                   const float* __restrict__ bg,
                                   const __hip_bfloat16* hin,
                                   __hip_bfloat16* hout,
                                   int wave, int m, int q)
{
    for (int nt = wave; nt < 8; nt += 2) {
        const int n0 = nt * 16;
        bf16x8 bfrag[K / 32];
#pragma unroll
        for (int kt = 0; kt < K / 32; kt++)
            bfrag[kt] = cvt8(&Wg[(n0 + m) * K + kt * 32 + q * 8]);
        const float bias = bg[n0 + m];
#pragma unroll
        for (int mt = 0; mt < 2; mt++) {
            f32x4 acc = {0.f, 0.f, 0.f, 0.f};
#pragma unroll
            for (int kt = 0; kt < K / 32; kt++) {
                bf16x8 afrag = *(const bf16x8*)&hin[(mt * 16 + m) * LDIN + kt * 32 + q * 8];
                acc = __builtin_amdgcn_mfma_f32_16x16x32_bf16(afrag, bfrag[kt], acc, 0, 0, 0);
            }
#pragma unroll
            for (int r = 0; r < 4; r++) {
                float v = fmaxf(acc[r] + bias, 0.f);
                hout[(mt * 16 + q * 4 + r) * LDH + n0 + m] = __float2bfloat16(v);
            }
        }
    }
}

__global__ __launch_bounds__(128)
void rqs_fused_kernel(const float* __restrict__ xg,
                      const float* __restrict__ W1g, const float* __restrict__ b1g,
                      const float* __restrict__ W2g, const float* __restrict__ b2g,
                      const float* __restrict__ W3g, const float* __restrict__ b3g,
                      const float* __restrict__ W4g, const float* __restrict__ b4g,
                      float* __restrict__ outg, int nrows)
{
    __shared__ __align__(16) __hip_bfloat16 sx[TM * LDXM];  //  2.5 KB : masked-x tile [32][32]
    __shared__ __align__(16) __hip_bfloat16 shA[TM * LDH];  //  8.7 KB : h1 / h3
    __shared__ __align__(16) __hip_bfloat16 shB[TM * LDH];  //  8.7 KB : h2
    __shared__ __align__(16) __hip_bfloat16 sp[TM * LDP];   // 26.6 KB : params chunk [32][16*26]

    const int tid  = threadIdx.x;
    const int wave = tid >> 6;
    const int lane = tid & 63;
    const int m    = lane & 15;
    const int q    = lane >> 4;
    const int row0 = blockIdx.x * TM;

    // ---- stage masked x (fp32 -> bf16) + exact fp32 passthrough of y[:, :32] ----
    {
        const int r = tid >> 2, quarter = tid & 3;           // 32 rows x 4 chunks of 8
        const float* src = &xg[(size_t)(row0 + r) * 64 + quarter * 8];
        f32x4 a = *(const f32x4*)src;
        f32x4 b = *(const f32x4*)(src + 4);
        float* dst = &outg[(size_t)(row0 + r) * 64 + quarter * 8];
        *(f32x4*)dst = a;
        *(f32x4*)(dst + 4) = b;
        bf16x8 v;
        v[0] = (__bf16)a[0]; v[1] = (__bf16)a[1]; v[2] = (__bf16)a[2]; v[3] = (__bf16)a[3];
        v[4] = (__bf16)b[0]; v[5] = (__bf16)b[1]; v[6] = (__bf16)b[2]; v[7] = (__bf16)b[3];
        *(bf16x8*)&sx[r * LDXM + quarter * 8] = v;
    }
    __syncthreads();

    // ---- MLP layers 1..3 ----
    dense_layer<32, LDXM>(W1g, b1g, sx, shA, wave, m, q);
    __syncthreads();
    dense_layer<128, LDH>(W2g, b2g, shA, shB, wave, m, q);
    __syncthreads();
    dense_layer<128, LDH>(W3g, b3g, shB, shA, wave, m, q);
    __syncthreads();
    // h3 now in shA

    float ldacc[4] = {0.f, 0.f, 0.f, 0.f};

    // ---- layer 4 + spline, in 2 chunks of 16 transform-dims (400 cols each) ----
    for (int chunk = 0; chunk < 2; chunk++) {
        for (int ntl = wave; ntl < 25; ntl += 2) {
            const int colg = chunk * 400 + ntl * 16 + m;     // global output col (0..799)
            bf16x8 bfrag[4];
#pragma unroll
            for (int kt = 0; kt < 4; kt++)
                bfrag[kt] = cvt8(&W4g[(size_t)colg * 128 + kt * 32 + q * 8]);
            const float bias = b4g[colg];
            const int coll = ntl * 16 + m;                   // 0..399 within chunk
            const int dl   = coll / 25;                      // dim-local 0..15
            const int spcol = dl * 26 + (coll - dl * 25);
#pragma unroll
            for (int mt = 0; mt < 2; mt++) {
                f32x4 acc = {0.f, 0.f, 0.f, 0.f};
#pragma unroll
                for (int kt = 0; kt < 4; kt++) {
                    bf16x8 afrag = *(const bf16x8*)&shA[(mt * 16 + m) * LDH + kt * 32 + q * 8];
                    acc = __builtin_amdgcn_mfma_f32_16x16x32_bf16(afrag, bfrag[kt], acc, 0, 0, 0);
                }
#pragma unroll
                for (int r = 0; r < 4; r++)
                    sp[(mt * 16 + q * 4 + r) * LDP + spcol] = __float2bfloat16(acc[r] + bias);
            }
        }
        __syncthreads();

        // spline: thread -> (dim = tid&15, rows rb+8i)
        const int dim = tid & 15;
        const int rb  = tid >> 4;
#pragma unroll
        for (int i = 0; i < 4; i++) {
            const int row = rb + 8 * i;
            const __hip_bfloat16* pr = &sp[row * LDP + dim * 26];
            float raw[25];
#pragma unroll
            for (int j = 0; j < 25; j++) raw[j] = __bfloat162float(pr[j]);

            float w_[8], h_[8], s_[9];
            float mw = raw[0];
#pragma unroll
            for (int j = 1; j < 8; j++) mw = fmaxf(mw, raw[j]);
            float sumw = 0.f;
#pragma unroll
            for (int j = 0; j < 8; j++) { w_[j] = __expf(raw[j] - mw); sumw += w_[j]; }
            float scw = (10.f - 8.f * MIN_BIN) / sumw;
#pragma unroll
            for (int j = 0; j < 8; j++) w_[j] = MIN_BIN + w_[j] * scw;

            float mh = raw[8];
#pragma unroll
            for (int j = 9; j < 16; j++) mh = fmaxf(mh, raw[j]);
            float sumh = 0.f;
#pragma unroll
            for (int j = 0; j < 8; j++) { h_[j] = __expf(raw[8 + j] - mh); sumh += h_[j]; }
            float sch = (10.f - 8.f * MIN_BIN) / sumh;
#pragma unroll
            for (int j = 0; j < 8; j++) h_[j] = MIN_BIN + h_[j] * sch;

#pragma unroll
            for (int j = 0; j < 9; j++) {
                float v = raw[16 + j];
                s_[j] = MIN_SLOPE + fmaxf(v, 0.f) + log1pf(__expf(-fabsf(v)));
            }

            const int gdim = chunk * 16 + dim;
            const float x = xg[(size_t)(row0 + row) * 64 + 32 + gdim];   // fp32, exact
            const bool inside = (x >= -5.f) && (x <= 5.f);
            const float xc = fminf(fmaxf(x, -5.f), 5.f);

            // sequential cumsum + bin select (matches jnp.cumsum order)
            float cx = -5.f, cy = -5.f;
            float xk = -5.f, yk = -5.f, wk = w_[0], hk = h_[0], dk = s_[0], dk1 = s_[1];
#pragma unroll
            for (int j = 0; j < 8; j++) {
                if (xc >= cx) { xk = cx; yk = cy; wk = w_[j]; hk = h_[j]; dk = s_[j]; dk1 = s_[j + 1]; }
                cx += w_[j]; cy += h_[j];
            }

            const float xi = (xc - xk) / wk;
            const float om = 1.f - xi;
            const float sk = hk / wk;
            const float den = sk + (dk1 + dk - 2.f * sk) * xi * om;
            const float y_in = yk + hk * (sk * xi * xi + dk * xi * om) / den;
            const float num = sk * sk * (dk1 * xi * xi + 2.f * sk * xi * om + dk * om * om);
            const float ld_in = __logf(num / (den * den));

            const float y = inside ? y_in : x;
            ldacc[i] += inside ? ld_in : 0.f;
            outg[(size_t)(row0 + row) * 64 + 32 + gdim] = y;
        }
        __syncthreads();
    }

    // ---- logdet: reduce over the 16 lanes (dims) sharing each row ----
#pragma unroll
    for (int i = 0; i < 4; i++) {
        float v = ldacc[i];
        v += __shfl_xor(v, 1);
        v += __shfl_xor(v, 2);
        v += __shfl_xor(v, 4);
        v += __shfl_xor(v, 8);
        if ((tid & 15) == 0) {
            int row = (tid >> 4) + 8 * i;
            outg[(size_t)nrows * 64 + row0 + row] = v;
        }
    }
}

extern "C" void kernel_launch(void* const* d_in, const int* in_sizes, int n_in,
                              void* d_out, int out_size, void* d_ws, size_t ws_size,
                              hipStream_t stream) {
    const float* x  = (const float*)d_in[0];
    const float* W1 = (const float*)d_in[1];
    const float* b1 = (const float*)d_in[2];
    const float* W2 = (const float*)d_in[3];
    const float* b2 = (const float*)d_in[4];
    const float* W3 = (const float*)d_in[5];
    const float* b3 = (const float*)d_in[6];
    const float* W4 = (const float*)d_in[7];
    const float* b4 = (const float*)d_in[8];
    float* out = (float*)d_out;

    const int nrows = in_sizes[0] / 64;   // 262144
    const int grid  = nrows / TM;         // 8192
    rqs_fused_kernel<<<grid, 128, 0, stream>>>(x, W1, b1, W2, b2, W3, b3, W4, b4, out, nrows);
}

// Round 5
// 349.558 us; speedup vs baseline: 2.3064x; 2.3064x over previous
//
#include <hip/hip_runtime.h>
#include <hip/hip_bf16.h>

typedef __attribute__((ext_vector_type(8))) __bf16 bf16x8;
typedef __attribute__((ext_vector_type(4))) __bf16 bf16x4;
typedef __attribute__((ext_vector_type(4))) float f32x4;
typedef unsigned int u32;

#define TM 64          // rows per block
#define LDXM 40        // masked-x tile stride (elements)
#define LDH 136        // h tile stride
#define LDP2 210       // params stride for 8-dim chunk (8*26 + 2 pad)
#define MIN_BIN 1e-4f
#define MIN_SLOPE 1e-4f

// bf16 weight cache layout in d_ws (element offsets)
#define OW1 0
#define OW2 4096
#define OW3 20480
#define OW4 36864
#define NWELEM 139264   // total weight elements (W1+W2+W3+W4)

// ---- prep: fp32 weights -> bf16 cache in workspace (runs every launch) ----
__global__ void prep_weights(const float* __restrict__ W1, const float* __restrict__ W2,
                             const float* __restrict__ W3, const float* __restrict__ W4,
                             __hip_bfloat16* __restrict__ ws) {
    int e = (blockIdx.x * blockDim.x + threadIdx.x) * 4;
    if (e >= NWELEM) return;
    const float* src;
    if (e < OW2)      src = W1 + e;
    else if (e < OW3) src = W2 + (e - OW2);
    else if (e < OW4) src = W3 + (e - OW3);
    else              src = W4 + (e - OW4);
    f32x4 v = *(const f32x4*)src;
    bf16x4 o;
    o[0] = (__bf16)v[0]; o[1] = (__bf16)v[1]; o[2] = (__bf16)v[2]; o[3] = (__bf16)v[3];
    *(bf16x4*)&ws[e] = o;
}

// load 8 contiguous fp32, convert to bf16x8 (fallback path)
__device__ inline bf16x8 cvt8(const float* __restrict__ p) {
    f32x4 a = *(const f32x4*)p;
    f32x4 b = *(const f32x4*)(p + 4);
    bf16x8 r;
    r[0] = (__bf16)a[0]; r[1] = (__bf16)a[1]; r[2] = (__bf16)a[2]; r[3] = (__bf16)a[3];
    r[4] = (__bf16)b[0]; r[5] = (__bf16)b[1]; r[6] = (__bf16)b[2]; r[7] = (__bf16)b[3];
    return r;
}

template<bool USE_WS>
__device__ inline bf16x8 wfrag(const __hip_bfloat16* __restrict__ wsW,
                               const float* __restrict__ Wg, size_t off) {
    if constexpr (USE_WS) return *(const bf16x8*)(wsW + off);
    else                  return cvt8(Wg + off);
}

// ---- one dense layer: hout = relu(hin @ W^T + b), N=128, MFMA 16x16x32 ----
// A-frag: hin[m0+(l&15)][kt*32+(l>>4)*8..+8]; B-frag: W[(n0+(l&15))*K + ...]
// C/D: col = n0+(l&15), row = m0 + (l>>4)*4 + reg
template<bool USE_WS, int K, int LDIN>
__device__ inline void dense_layer(const __hip_bfloat16* __restrict__ wsW,
                                   const float* __restrict__ Wg,
                                   const float* __restrict__ bg,
                                   const __hip_bfloat16* hin,
                                   __hip_bfloat16* hout,
                                   int wave, int m, int q)
{
    for (int nt = wave; nt < 8; nt += 4) {
        const int n0 = nt * 16;
        bf16x8 bfrag[K / 32];
#pragma unroll
        for (int kt = 0; kt < K / 32; kt++)
            bfrag[kt] = wfrag<USE_WS>(wsW, Wg, (size_t)(n0 + m) * K + kt * 32 + q * 8);
        const float bias = bg[n0 + m];
#pragma unroll
        for (int mt = 0; mt < 4; mt++) {
            f32x4 acc = {0.f, 0.f, 0.f, 0.f};
#pragma unroll
            for (int kt = 0; kt < K / 32; kt++) {
                bf16x8 afrag = *(const bf16x8*)&hin[(mt * 16 + m) * LDIN + kt * 32 + q * 8];
                acc = __builtin_amdgcn_mfma_f32_16x16x32_bf16(afrag, bfrag[kt], acc, 0, 0, 0);
            }
#pragma unroll
            for (int r = 0; r < 4; r++) {
                float v = fmaxf(acc[r] + bias, 0.f);
                hout[(mt * 16 + q * 4 + r) * LDH + n0 + m] = __float2bfloat16(v);
            }
        }
    }
}

template<bool USE_WS>
__global__ __launch_bounds__(256, 3)
void rqs_fused_kernel(const float* __restrict__ xg,
                      const float* __restrict__ W1g, const float* __restrict__ b1g,
                      const float* __restrict__ W2g, const float* __restrict__ b2g,
                      const float* __restrict__ W3g, const float* __restrict__ b3g,
                      const float* __restrict__ W4g, const float* __restrict__ b4g,
                      const __hip_bfloat16* __restrict__ ws,
                      float* __restrict__ outg, int nrows)
{
    // phase-union LDS: [shA 17408 | {sx 5120 + shB 17408} / {sp 26880}]
    __shared__ __align__(16) unsigned char smem[17408 + 26880];
    __hip_bfloat16* const shA = (__hip_bfloat16*)smem;              // h1/h3 [64][136]
    __hip_bfloat16* const sx  = (__hip_bfloat16*)(smem + 17408);    // x_masked [64][40]
    __hip_bfloat16* const shB = (__hip_bfloat16*)(smem + 22528);    // h2 [64][136]
    __hip_bfloat16* const sp  = (__hip_bfloat16*)(smem + 17408);    // params [64][210]

    const int tid  = threadIdx.x;
    const int wave = tid >> 6;
    const int lane = tid & 63;
    const int m    = lane & 15;
    const int q    = lane >> 4;
    const int row0 = blockIdx.x * TM;

    // ---- stage masked x (fp32->bf16) + exact fp32 passthrough y[:, :32] ----
    {
        const int r = tid >> 2, q8 = tid & 3;                 // 64 rows x 4 chunks of 8
        const float* src = &xg[(size_t)(row0 + r) * 64 + q8 * 8];
        f32x4 a = *(const f32x4*)src;
        f32x4 b = *(const f32x4*)(src + 4);
        float* dst = &outg[(size_t)(row0 + r) * 64 + q8 * 8];
        *(f32x4*)dst = a;
        *(f32x4*)(dst + 4) = b;
        bf16x8 v;
        v[0] = (__bf16)a[0]; v[1] = (__bf16)a[1]; v[2] = (__bf16)a[2]; v[3] = (__bf16)a[3];
        v[4] = (__bf16)b[0]; v[5] = (__bf16)b[1]; v[6] = (__bf16)b[2]; v[7] = (__bf16)b[3];
        *(bf16x8*)&sx[r * LDXM + q8 * 8] = v;
    }
    __syncthreads();

    // ---- MLP layers 1..3 ----
    dense_layer<USE_WS, 32, LDXM>(ws + OW1, W1g, b1g, sx, shA, wave, m, q);
    __syncthreads();
    dense_layer<USE_WS, 128, LDH>(ws + OW2, W2g, b2g, shA, shB, wave, m, q);
    __syncthreads();
    dense_layer<USE_WS, 128, LDH>(ws + OW3, W3g, b3g, shB, shA, wave, m, q);
    __syncthreads();
    // h3 persists in shA across all chunks; sx/shB now dead -> sp overlays them

    float ldacc[2] = {0.f, 0.f};

    // ---- layer 4 + spline, 4 chunks of 8 transform-dims (200 cols each) ----
    for (int c = 0; c < 4; c++) {
        const int t0 = (25 * c) >> 1;                 // first tile: 0,12,25,37
        for (int tt = wave; tt < 13; tt += 4) {
            const int nt   = t0 + tt;
            const int colg = nt * 16 + m;             // 0..799
            bf16x8 bfrag[4];
#pragma unroll
            for (int kt = 0; kt < 4; kt++)
                bfrag[kt] = wfrag<USE_WS>(ws + OW4, W4g, (size_t)colg * 128 + kt * 32 + q * 8);
            const float bias = b4g[colg];
            const int lc = colg - 200 * c;            // col within chunk
            const bool ok = (lc >= 0) && (lc < 200);
            const int lcc = ok ? lc : 0;
            const int dl  = lcc / 25;
            const int spcol = dl * 26 + (lcc - dl * 25);
#pragma unroll
            for (int mt = 0; mt < 4; mt++) {
                f32x4 acc = {0.f, 0.f, 0.f, 0.f};
#pragma unroll
                for (int kt = 0; kt < 4; kt++) {
                    bf16x8 afrag = *(const bf16x8*)&shA[(mt * 16 + m) * LDH + kt * 32 + q * 8];
                    acc = __builtin_amdgcn_mfma_f32_16x16x32_bf16(afrag, bfrag[kt], acc, 0, 0, 0);
                }
                if (ok) {
#pragma unroll
                    for (int r = 0; r < 4; r++)
                        sp[(mt * 16 + q * 4 + r) * LDP2 + spcol] = __float2bfloat16(acc[r] + bias);
                }
            }
        }
        __syncthreads();

        // ---- spline: thread -> (dim = tid&7, rows (tid>>3) + 32*i) ----
        const int dim = tid & 7;
        const int rb  = tid >> 3;
#pragma unroll
        for (int i = 0; i < 2; i++) {
            const int row = rb + 32 * i;
            const __hip_bfloat16* pr = &sp[row * LDP2 + dim * 26];
            float raw[25];
            const u32* pu = (const u32*)pr;           // 4B-aligned: 420*row + 52*dim
#pragma unroll
            for (int j = 0; j < 12; j++) {
                u32 u = pu[j];
                raw[2 * j]     = __uint_as_float(u << 16);
                raw[2 * j + 1] = __uint_as_float(u & 0xffff0000u);
            }
            raw[24] = __bfloat162float(pr[24]);

            float ew[8], eh[8];
            float mw = raw[0], mh = raw[8];
#pragma unroll
            for (int j = 1; j < 8; j++) { mw = fmaxf(mw, raw[j]); mh = fmaxf(mh, raw[8 + j]); }
            float sumw = 0.f, sumh = 0.f;
#pragma unroll
            for (int j = 0; j < 8; j++) {
                ew[j] = __expf(raw[j] - mw);      sumw += ew[j];
                eh[j] = __expf(raw[8 + j] - mh);  sumh += eh[j];
            }
            const float scw = (10.f - 8.f * MIN_BIN) / sumw;
            const float sch = (10.f - 8.f * MIN_BIN) / sumh;

            const int gdim = c * 8 + dim;
            const float x = xg[(size_t)(row0 + row) * 64 + 32 + gdim];
            const bool inside = (x >= -5.f) && (x <= 5.f);
            const float xc = fminf(fmaxf(x, -5.f), 5.f);

            // sequential cumsum + bin select (matches jnp.cumsum order)
            float cx = -5.f, cy = -5.f;
            float xk = -5.f, yk = -5.f, wk = 0.f, hk = 0.f, r0 = 0.f, r1 = 0.f;
#pragma unroll
            for (int j = 0; j < 8; j++) {
                const float wj = fmaf(ew[j], scw, MIN_BIN);
                const float hj = fmaf(eh[j], sch, MIN_BIN);
                const bool sel = xc >= cx;
                xk = sel ? cx : xk;  yk = sel ? cy : yk;
                wk = sel ? wj : wk;  hk = sel ? hj : hk;
                r0 = sel ? raw[16 + j] : r0;
                r1 = sel ? raw[17 + j] : r1;
                cx += wj; cy += hj;
            }

            // softplus only on the two selected slopes
            const float dk  = MIN_SLOPE + fmaxf(r0, 0.f) + log1pf(__expf(-fabsf(r0)));
            const float dk1 = MIN_SLOPE + fmaxf(r1, 0.f) + log1pf(__expf(-fabsf(r1)));

            const float rw = 1.f / wk;
            const float xi = (xc - xk) * rw;
            const float om = 1.f - xi;
            const float sk = hk * rw;
            const float xo = xi * om;
            const float den = fmaf(dk1 + dk - 2.f * sk, xo, sk);
            const float rden = 1.f / den;
            const float y_in = fmaf(hk * fmaf(sk * xi, xi, dk * xo), rden, yk);
            const float num = sk * sk * (fmaf(dk1 * xi, xi, dk * om * om) + 2.f * sk * xo);
            const float ld_in = __logf(num * rden * rden);

            outg[(size_t)(row0 + row) * 64 + 32 + gdim] = inside ? y_in : x;
            ldacc[i] += inside ? ld_in : 0.f;
        }
        __syncthreads();
    }

    // ---- logdet: reduce over the 8 lanes (dims) sharing each row, all chunks done ----
#pragma unroll
    for (int i = 0; i < 2; i++) {
        float v = ldacc[i];
        v += __shfl_xor(v, 1);
        v += __shfl_xor(v, 2);
        v += __shfl_xor(v, 4);
        if ((tid & 7) == 0) {
            int row = (tid >> 3) + 32 * i;
            outg[(size_t)nrows * 64 + row0 + row] = v;
        }
    }
}

extern "C" void kernel_launch(void* const* d_in, const int* in_sizes, int n_in,
                              void* d_out, int out_size, void* d_ws, size_t ws_size,
                              hipStream_t stream) {
    const float* x  = (const float*)d_in[0];
    const float* W1 = (const float*)d_in[1];
    const float* b1 = (const float*)d_in[2];
    const float* W2 = (const float*)d_in[3];
    const float* b2 = (const float*)d_in[4];
    const float* W3 = (const float*)d_in[5];
    const float* b3 = (const float*)d_in[6];
    const float* W4 = (const float*)d_in[7];
    const float* b4 = (const float*)d_in[8];
    float* out = (float*)d_out;
    __hip_bfloat16* ws = (__hip_bfloat16*)d_ws;

    const int nrows = in_sizes[0] / 64;   // 262144
    const int grid  = nrows / TM;         // 4096
    const bool use_ws = ws_size >= (size_t)NWELEM * 2;

    if (use_ws) {
        prep_weights<<<(NWELEM / 4 + 255) / 256, 256, 0, stream>>>(W1, W2, W3, W4, ws);
        rqs_fused_kernel<true><<<grid, 256, 0, stream>>>(x, W1, b1, W2, b2, W3, b3, W4, b4,
                                                         ws, out, nrows);
    } else {
        rqs_fused_kernel<false><<<grid, 256, 0, stream>>>(x, W1, b1, W2, b2, W3, b3, W4, b4,
                                                          ws, out, nrows);
    }
}

// Round 6
// 320.892 us; speedup vs baseline: 2.5124x; 1.0893x over previous
//
#include <hip/hip_runtime.h>
#include <hip/hip_bf16.h>

typedef __attribute__((ext_vector_type(8))) __bf16 bf16x8;
typedef __attribute__((ext_vector_type(4))) __bf16 bf16x4;
typedef __attribute__((ext_vector_type(4))) float f32x4;
typedef unsigned int u32;

#define TM 64          // rows per block
#define LDXM 40        // masked-x tile stride (elements)
#define LDH 136        // h tile stride (elements)
#define LDP 104        // params stride: 4 dims * 26 elems; 52 dwords -> bank = 13*lane (bijective mod 32)
#define MIN_BIN 1e-4f
#define MIN_SLOPE 1e-4f

// bf16 weight cache layout in d_ws (element offsets)
#define OW1 0
#define OW2 4096
#define OW3 20480
#define OW4 36864
#define NWELEM 139264   // total weight elements (W1+W2+W3+W4)

// ---- prep: fp32 weights -> bf16 cache in workspace (runs every launch) ----
__global__ void prep_weights(const float* __restrict__ W1, const float* __restrict__ W2,
                             const float* __restrict__ W3, const float* __restrict__ W4,
                             __hip_bfloat16* __restrict__ ws) {
    int e = (blockIdx.x * blockDim.x + threadIdx.x) * 4;
    if (e >= NWELEM) return;
    const float* src;
    if (e < OW2)      src = W1 + e;
    else if (e < OW3) src = W2 + (e - OW2);
    else if (e < OW4) src = W3 + (e - OW3);
    else              src = W4 + (e - OW4);
    f32x4 v = *(const f32x4*)src;
    bf16x4 o;
    o[0] = (__bf16)v[0]; o[1] = (__bf16)v[1]; o[2] = (__bf16)v[2]; o[3] = (__bf16)v[3];
    *(bf16x4*)&ws[e] = o;
}

// load 8 contiguous fp32, convert to bf16x8 (fallback path)
__device__ inline bf16x8 cvt8(const float* __restrict__ p) {
    f32x4 a = *(const f32x4*)p;
    f32x4 b = *(const f32x4*)(p + 4);
    bf16x8 r;
    r[0] = (__bf16)a[0]; r[1] = (__bf16)a[1]; r[2] = (__bf16)a[2]; r[3] = (__bf16)a[3];
    r[4] = (__bf16)b[0]; r[5] = (__bf16)b[1]; r[6] = (__bf16)b[2]; r[7] = (__bf16)b[3];
    return r;
}

template<bool USE_WS>
__device__ inline bf16x8 wfrag(const __hip_bfloat16* __restrict__ wsW,
                               const float* __restrict__ Wg, size_t off) {
    if constexpr (USE_WS) return *(const bf16x8*)(wsW + off);
    else                  return cvt8(Wg + off);
}

// ---- one dense layer: hout = relu(hin @ W^T + b), N=128, MFMA 16x16x32 ----
// A-frag: hin[m0+(l&15)][kt*32+(l>>4)*8..+8]; B-frag: W[(n0+(l&15))*K + ...]
// C/D: col = n0+(l&15), row = m0 + (l>>4)*4 + reg
template<bool USE_WS, int K, int LDIN>
__device__ inline void dense_layer(const __hip_bfloat16* __restrict__ wsW,
                                   const float* __restrict__ Wg,
                                   const float* __restrict__ bg,
                                   const __hip_bfloat16* hin,
                                   __hip_bfloat16* hout,
                                   int wave, int m, int q)
{
    for (int nt = wave; nt < 8; nt += 4) {
        const int n0 = nt * 16;
        bf16x8 bfrag[K / 32];
#pragma unroll
        for (int kt = 0; kt < K / 32; kt++)
            bfrag[kt] = wfrag<USE_WS>(wsW, Wg, (size_t)(n0 + m) * K + kt * 32 + q * 8);
        const float bias = bg[n0 + m];
#pragma unroll
        for (int mt = 0; mt < 4; mt++) {
            f32x4 acc = {0.f, 0.f, 0.f, 0.f};
#pragma unroll
            for (int kt = 0; kt < K / 32; kt++) {
                bf16x8 afrag = *(const bf16x8*)&hin[(mt * 16 + m) * LDIN + kt * 32 + q * 8];
                acc = __builtin_amdgcn_mfma_f32_16x16x32_bf16(afrag, bfrag[kt], acc, 0, 0, 0);
            }
#pragma unroll
            for (int r = 0; r < 4; r++) {
                float v = fmaxf(acc[r] + bias, 0.f);
                hout[(mt * 16 + q * 4 + r) * LDH + n0 + m] = __float2bfloat16(v);
            }
        }
    }
}

template<bool USE_WS>
__global__ __launch_bounds__(256, 4)
void rqs_fused_kernel(const float* __restrict__ xg,
                      const float* __restrict__ W1g, const float* __restrict__ b1g,
                      const float* __restrict__ W2g, const float* __restrict__ b2g,
                      const float* __restrict__ W3g, const float* __restrict__ b3g,
                      const float* __restrict__ W4g, const float* __restrict__ b4g,
                      const __hip_bfloat16* __restrict__ ws,
                      float* __restrict__ outg, int nrows)
{
    // LDS 34 KB total -> 4 blocks/CU.  shB region is overlaid by sx (layer-1 input)
    // and later by sp (spline params), both lifetimes disjoint from shB (h2).
    __shared__ __align__(16) unsigned char smem[17408 + 17408];
    __hip_bfloat16* const shA = (__hip_bfloat16*)smem;              // h1/h3 [64][136]
    __hip_bfloat16* const shB = (__hip_bfloat16*)(smem + 17408);    // h2 [64][136]
    __hip_bfloat16* const sx  = (__hip_bfloat16*)(smem + 17408);    // x_masked [64][40]
    __hip_bfloat16* const sp  = (__hip_bfloat16*)(smem + 17408);    // params [64][104]

    const int tid  = threadIdx.x;
    const int wave = tid >> 6;
    const int lane = tid & 63;
    const int m    = lane & 15;
    const int q    = lane >> 4;
    const int row0 = blockIdx.x * TM;

    // ---- stage masked x (fp32->bf16) + exact fp32 passthrough y[:, :32] ----
    {
        const int r = tid >> 2, q8 = tid & 3;                 // 64 rows x 4 chunks of 8
        const float* src = &xg[(size_t)(row0 + r) * 64 + q8 * 8];
        f32x4 a = *(const f32x4*)src;
        f32x4 b = *(const f32x4*)(src + 4);
        float* dst = &outg[(size_t)(row0 + r) * 64 + q8 * 8];
        *(f32x4*)dst = a;
        *(f32x4*)(dst + 4) = b;
        bf16x8 v;
        v[0] = (__bf16)a[0]; v[1] = (__bf16)a[1]; v[2] = (__bf16)a[2]; v[3] = (__bf16)a[3];
        v[4] = (__bf16)b[0]; v[5] = (__bf16)b[1]; v[6] = (__bf16)b[2]; v[7] = (__bf16)b[3];
        *(bf16x8*)&sx[r * LDXM + q8 * 8] = v;
    }
    __syncthreads();

    // ---- MLP layers 1..3 ----
    dense_layer<USE_WS, 32, LDXM>(ws + OW1, W1g, b1g, sx, shA, wave, m, q);
    __syncthreads();
    dense_layer<USE_WS, 128, LDH>(ws + OW2, W2g, b2g, shA, shB, wave, m, q);
    __syncthreads();
    dense_layer<USE_WS, 128, LDH>(ws + OW3, W3g, b3g, shB, shA, wave, m, q);
    __syncthreads();
    // h3 persists in shA across all chunks; shB/sx dead -> sp overlays

    float ldacc = 0.f;
    const int dim = tid & 3;                  // spline: fixed (row, 4-dim lane group)
    const int srow = tid >> 2;                // 0..63 — covers all rows each chunk

    // ---- layer 4 + spline, 8 chunks of 4 transform-dims (100 cols each) ----
    for (int c = 0; c < 8; c++) {
        const int t0 = (25 * c) >> 2;                 // first tile: 0,6,12,18,25,31,37,43
        for (int tt = wave; tt < 7; tt += 4) {
            const int nt   = t0 + tt;
            const int colg = nt * 16 + m;             // 0..799
            bf16x8 bfrag[4];
#pragma unroll
            for (int kt = 0; kt < 4; kt++)
                bfrag[kt] = wfrag<USE_WS>(ws + OW4, W4g, (size_t)colg * 128 + kt * 32 + q * 8);
            const float bias = b4g[colg];
            const int lc = colg - 100 * c;            // col within chunk
            const bool ok = (lc >= 0) && (lc < 100);
            const int lcc = ok ? lc : 0;
            const int dl  = lcc / 25;
            const int spcol = dl * 26 + (lcc - dl * 25);
#pragma unroll
            for (int mt = 0; mt < 4; mt++) {
                f32x4 acc = {0.f, 0.f, 0.f, 0.f};
#pragma unroll
                for (int kt = 0; kt < 4; kt++) {
                    bf16x8 afrag = *(const bf16x8*)&shA[(mt * 16 + m) * LDH + kt * 32 + q * 8];
                    acc = __builtin_amdgcn_mfma_f32_16x16x32_bf16(afrag, bfrag[kt], acc, 0, 0, 0);
                }
                if (ok) {
#pragma unroll
                    for (int r = 0; r < 4; r++)
                        sp[(mt * 16 + q * 4 + r) * LDP + spcol] = __float2bfloat16(acc[r] + bias);
                }
            }
        }
        __syncthreads();

        // ---- spline: one (row, dim) cell per thread ----
        {
            const __hip_bfloat16* pr = &sp[srow * LDP + dim * 26];
            float raw[25];
            const u32* pu = (const u32*)pr;           // dword idx = 13*lane + j : conflict-free
#pragma unroll
            for (int j = 0; j < 12; j++) {
                u32 u = pu[j];
                raw[2 * j]     = __uint_as_float(u << 16);
                raw[2 * j + 1] = __uint_as_float(u & 0xffff0000u);
            }
            raw[24] = __bfloat162float(pr[24]);

            float ew[8], eh[8];
            float mw = raw[0], mh = raw[8];
#pragma unroll
            for (int j = 1; j < 8; j++) { mw = fmaxf(mw, raw[j]); mh = fmaxf(mh, raw[8 + j]); }
            float sumw = 0.f, sumh = 0.f;
#pragma unroll
            for (int j = 0; j < 8; j++) {
                ew[j] = __expf(raw[j] - mw);      sumw += ew[j];
                eh[j] = __expf(raw[8 + j] - mh);  sumh += eh[j];
            }
            const float scw = (10.f - 8.f * MIN_BIN) / sumw;
            const float sch = (10.f - 8.f * MIN_BIN) / sumh;

            const int gdim = c * 4 + dim;
            const float x = xg[(size_t)(row0 + srow) * 64 + 32 + gdim];
            const bool inside = (x >= -5.f) && (x <= 5.f);
            const float xc = fminf(fmaxf(x, -5.f), 5.f);

            // sequential cumsum + bin select (matches jnp.cumsum order)
            float cx = -5.f, cy = -5.f;
            float xk = -5.f, yk = -5.f, wk = 0.f, hk = 0.f, r0 = 0.f, r1 = 0.f;
#pragma unroll
            for (int j = 0; j < 8; j++) {
                const float wj = fmaf(ew[j], scw, MIN_BIN);
                const float hj = fmaf(eh[j], sch, MIN_BIN);
                const bool sel = xc >= cx;
                xk = sel ? cx : xk;  yk = sel ? cy : yk;
                wk = sel ? wj : wk;  hk = sel ? hj : hk;
                r0 = sel ? raw[16 + j] : r0;
                r1 = sel ? raw[17 + j] : r1;
                cx += wj; cy += hj;
            }

            // softplus only on the two selected slopes
            const float dk  = MIN_SLOPE + fmaxf(r0, 0.f) + log1pf(__expf(-fabsf(r0)));
            const float dk1 = MIN_SLOPE + fmaxf(r1, 0.f) + log1pf(__expf(-fabsf(r1)));

            const float rw = 1.f / wk;
            const float xi = (xc - xk) * rw;
            const float om = 1.f - xi;
            const float sk = hk * rw;
            const float xo = xi * om;
            const float den = fmaf(dk1 + dk - 2.f * sk, xo, sk);
            const float rden = 1.f / den;
            const float y_in = fmaf(hk * fmaf(sk * xi, xi, dk * xo), rden, yk);
            const float num = sk * sk * (fmaf(dk1 * xi, xi, dk * om * om) + 2.f * sk * xo);
            const float ld_in = __logf(num * rden * rden);

            outg[(size_t)(row0 + srow) * 64 + 32 + gdim] = inside ? y_in : x;
            ldacc += inside ? ld_in : 0.f;
        }
        __syncthreads();
    }

    // ---- logdet: reduce over the 4 lanes (dim groups) sharing each row ----
    {
        float v = ldacc;
        v += __shfl_xor(v, 1);
        v += __shfl_xor(v, 2);
        if (dim == 0)
            outg[(size_t)nrows * 64 + row0 + srow] = v;
    }
}

extern "C" void kernel_launch(void* const* d_in, const int* in_sizes, int n_in,
                              void* d_out, int out_size, void* d_ws, size_t ws_size,
                              hipStream_t stream) {
    const float* x  = (const float*)d_in[0];
    const float* W1 = (const float*)d_in[1];
    const float* b1 = (const float*)d_in[2];
    const float* W2 = (const float*)d_in[3];
    const float* b2 = (const float*)d_in[4];
    const float* W3 = (const float*)d_in[5];
    const float* b3 = (const float*)d_in[6];
    const float* W4 = (const float*)d_in[7];
    const float* b4 = (const float*)d_in[8];
    float* out = (float*)d_out;
    __hip_bfloat16* ws = (__hip_bfloat16*)d_ws;

    const int nrows = in_sizes[0] / 64;   // 262144
    const int grid  = nrows / TM;         // 4096
    const bool use_ws = ws_size >= (size_t)NWELEM * 2;

    if (use_ws) {
        prep_weights<<<(NWELEM / 4 + 255) / 256, 256, 0, stream>>>(W1, W2, W3, W4, ws);
        rqs_fused_kernel<true><<<grid, 256, 0, stream>>>(x, W1, b1, W2, b2, W3, b3, W4, b4,
                                                         ws, out, nrows);
    } else {
        rqs_fused_kernel<false><<<grid, 256, 0, stream>>>(x, W1, b1, W2, b2, W3, b3, W4, b4,
                                                          ws, out, nrows);
    }
}